// Round 5
// baseline (25.975 us; speedup 1.0000x reference)
//
#include <hip/hip_runtime.h>

// RoiPoolingConv: crop-and-resize bilinear, img (1,64,64,1024) f32, 512 ROIs,
// 7x7 pool -> out (1,512,7,7,1024) f32.
//
// Channel-slab decomposition: 8 slabs x 128 channels, slab = blockIdx & 7 so
// under round-robin block->XCD dispatch each XCD only reads its 2 MB image
// slab -> L2-resident. NT stores keep the write stream from evicting the slab.
// 2048 blocks, 8 blocks/CU = 32 waves/CU (max occupancy).
//
// R4 change: 2 float4 units per thread per iteration -> 8 gathers in flight
// before the dependent lerp+store (MLP doubling), 6 full iters + 64-unit tail.

#define POOLSZ 7
#define NROIS  512
#define IMG_H  64
#define IMG_W  64
#define IMG_C  1024
#define NSLAB  8
#define SLABC  (IMG_C / NSLAB)     // 128
#define CELLS  (POOLSZ * POOLSZ)   // 49
#define RPB    2                   // ROIs per block
#define UNITS  (RPB * CELLS * 32)  // 3136 float4 units per block

typedef float fvec4 __attribute__((ext_vector_type(4)));

__device__ __forceinline__ void unit_coords(
    int unit, const int sYi0[RPB][POOLSZ], const int sYi1[RPB][POOLSZ],
    const float sFy[RPB][POOLSZ], const int sXi0[RPB][POOLSZ],
    const int sXi1[RPB][POOLSZ], const float sFx[RPB][POOLSZ],
    int slab, int& rl, int& cell, size_t& b00, size_t& b01, size_t& b10,
    size_t& b11, float& fx, float& fy, int& c)
{
    const int cellg = unit >> 5;
    const int lane  = unit & 31;
    rl   = cellg / CELLS;
    cell = cellg - rl * CELLS;
    const int py = cell / POOLSZ;
    const int px = cell - py * POOLSZ;

    const int yi0 = sYi0[rl][py];
    const int yi1 = sYi1[rl][py];
    fy            = sFy [rl][py];
    const int xi0 = sXi0[rl][px];
    const int xi1 = sXi1[rl][px];
    fx            = sFx [rl][px];

    c = slab * SLABC + lane * 4;
    b00 = ((size_t)(yi0 * IMG_W + xi0)) * IMG_C + c;
    b01 = ((size_t)(yi0 * IMG_W + xi1)) * IMG_C + c;
    b10 = ((size_t)(yi1 * IMG_W + xi0)) * IMG_C + c;
    b11 = ((size_t)(yi1 * IMG_W + xi1)) * IMG_C + c;
}

__global__ __launch_bounds__(256, 8) void roi_pool_kernel(
    const float* __restrict__ img,
    const int*   __restrict__ rois,
    float*       __restrict__ out)
{
    __shared__ int   sYi0[RPB][POOLSZ], sYi1[RPB][POOLSZ];
    __shared__ float sFy [RPB][POOLSZ];
    __shared__ int   sXi0[RPB][POOLSZ], sXi1[RPB][POOLSZ];
    __shared__ float sFx [RPB][POOLSZ];

    const int bid     = blockIdx.x;
    const int slab    = bid & (NSLAB - 1);     // pins slab to XCD (round-robin)
    const int roibase = (bid >> 3) * RPB;

    const int t = threadIdx.x;

    // --- setup: 28 threads compute the per-ROI, per-axis coord triples ---
    if (t < RPB * 2 * POOLSZ) {
        const int rl   = t / (2 * POOLSZ);
        const int j    = t % (2 * POOLSZ);
        const int axis = j / POOLSZ;            // 0 = y, 1 = x
        const int p    = j % POOLSZ;
        const int r    = roibase + rl;

        const int x1 = rois[r * 4 + 0];
        const int y1 = rois[r * 4 + 1];
        const int w  = rois[r * 4 + 2];
        const int h  = rois[r * 4 + 3];

        const int start = axis ? x1 : y1;
        const int lim   = axis ? IMG_W : IMG_H;
        const int ext   = axis ? w : h;
        const int eff   = min(start + ext, lim) - start;
        const float efff = (float)eff;

        // Exactly the reference arithmetic: t = (p+0.5)*eff/POOL - 0.5
        const float tq = (p + 0.5f) * efff / (float)POOLSZ - 0.5f;
        const float f0 = floorf(tq);
        const float fr = tq - f0;
        const int i0 = (int)fminf(fmaxf(f0,        0.0f), efff - 1.0f) + start;
        const int i1 = (int)fminf(fmaxf(f0 + 1.0f, 0.0f), efff - 1.0f) + start;

        if (axis == 0) { sYi0[rl][p] = i0; sYi1[rl][p] = i1; sFy[rl][p] = fr; }
        else           { sXi0[rl][p] = i0; sXi1[rl][p] = i1; sFx[rl][p] = fr; }
    }
    __syncthreads();

    // --- main loop: 2 units per thread per iteration, 6 full iters ---
    #pragma unroll
    for (int it = 0; it < 6; ++it) {
        const int unitA = it * 512 + t;
        const int unitB = unitA + 256;

        int rlA, cellA, cA, rlB, cellB, cB;
        size_t a00, a01, a10, a11, b00, b01, b10, b11;
        float fxA, fyA, fxB, fyB;
        unit_coords(unitA, sYi0, sYi1, sFy, sXi0, sXi1, sFx, slab,
                    rlA, cellA, a00, a01, a10, a11, fxA, fyA, cA);
        unit_coords(unitB, sYi0, sYi1, sFy, sXi0, sXi1, sFx, slab,
                    rlB, cellB, b00, b01, b10, b11, fxB, fyB, cB);

        // issue all 8 gathers before any dependent math
        const fvec4 vA00 = *reinterpret_cast<const fvec4*>(img + a00);
        const fvec4 vA01 = *reinterpret_cast<const fvec4*>(img + a01);
        const fvec4 vA10 = *reinterpret_cast<const fvec4*>(img + a10);
        const fvec4 vA11 = *reinterpret_cast<const fvec4*>(img + a11);
        const fvec4 vB00 = *reinterpret_cast<const fvec4*>(img + b00);
        const fvec4 vB01 = *reinterpret_cast<const fvec4*>(img + b01);
        const fvec4 vB10 = *reinterpret_cast<const fvec4*>(img + b10);
        const fvec4 vB11 = *reinterpret_cast<const fvec4*>(img + b11);

        const fvec4 topA = vA00 + (vA01 - vA00) * fxA;
        const fvec4 botA = vA10 + (vA11 - vA10) * fxA;
        const fvec4 oA   = topA + (botA - topA) * fyA;
        const fvec4 topB = vB00 + (vB01 - vB00) * fxB;
        const fvec4 botB = vB10 + (vB11 - vB10) * fxB;
        const fvec4 oB   = topB + (botB - topB) * fyB;

        const size_t oaA = ((size_t)((roibase + rlA) * CELLS + cellA)) * IMG_C + cA;
        const size_t oaB = ((size_t)((roibase + rlB) * CELLS + cellB)) * IMG_C + cB;
        __builtin_nontemporal_store(oA, reinterpret_cast<fvec4*>(out + oaA));
        __builtin_nontemporal_store(oB, reinterpret_cast<fvec4*>(out + oaB));
    }

    // --- tail: units 3072..3135 (threads 0..63) ---
    if (t < UNITS - 3072) {
        const int unit = 3072 + t;
        int rl, cell, c;
        size_t b00, b01, b10, b11;
        float fx, fy;
        unit_coords(unit, sYi0, sYi1, sFy, sXi0, sXi1, sFx, slab,
                    rl, cell, b00, b01, b10, b11, fx, fy, c);

        const fvec4 v00 = *reinterpret_cast<const fvec4*>(img + b00);
        const fvec4 v01 = *reinterpret_cast<const fvec4*>(img + b01);
        const fvec4 v10 = *reinterpret_cast<const fvec4*>(img + b10);
        const fvec4 v11 = *reinterpret_cast<const fvec4*>(img + b11);

        const fvec4 top = v00 + (v01 - v00) * fx;
        const fvec4 bot = v10 + (v11 - v10) * fx;
        const fvec4 o   = top + (bot - top) * fy;

        const size_t oa = ((size_t)((roibase + rl) * CELLS + cell)) * IMG_C + c;
        __builtin_nontemporal_store(o, reinterpret_cast<fvec4*>(out + oa));
    }
}

extern "C" void kernel_launch(void* const* d_in, const int* in_sizes, int n_in,
                              void* d_out, int out_size, void* d_ws, size_t ws_size,
                              hipStream_t stream) {
    const float* img  = (const float*)d_in[0];
    const int*   rois = (const int*)d_in[1];
    float*       out  = (float*)d_out;

    const int nblocks = (NROIS / RPB) * NSLAB;  // 2048 blocks, 256 threads
    roi_pool_kernel<<<nblocks, 256, 0, stream>>>(img, rois, out);
}